// Round 7
// baseline (372.061 us; speedup 1.0000x reference)
//
#include <hip/hip_runtime.h>
#include <hip/hip_bf16.h>

#define N_NODES 100000
#define N_FEATS 512
#define HIDDEN 64
#define NUM_SAMPLES 5
#define NUM_CLASSES 16
#define BATCH 16384

typedef __attribute__((ext_vector_type(8))) short bf16x8;
typedef __attribute__((ext_vector_type(8))) unsigned short u16x8;
typedef __attribute__((ext_vector_type(4))) float f32x4;

static __device__ __forceinline__ float bf2f(unsigned short s) {
    unsigned int u = ((unsigned int)s) << 16;
    return __builtin_bit_cast(float, u);
}
static __device__ __forceinline__ short f2bf(float v) {
    __hip_bfloat16 b = __float2bfloat16(v);
    return *reinterpret_cast<short*>(&b);
}
static __device__ __forceinline__ int clampi(int v) {
    return ((unsigned)v < (unsigned)N_NODES) ? v : 0;
}

// prep: (a) repack w1 [64][1024] fp32 into bf16 MFMA-fragment order:
// w1p[((kk*8 + nb)*64 + lane)*8 + j] = w1[h][part*512 + kk*32 + quad*8 + j]
// (b) detect whether `nodes` is int64 (odd int32 words all zero).
__global__ __launch_bounds__(256) void prep(const float* __restrict__ w1f,
                                            short* __restrict__ w1p,
                                            const int* __restrict__ nodes_i32,
                                            int* __restrict__ flag) {
    const int t = blockIdx.x * 256 + threadIdx.x;  // 0..65535
    if (t < 64 * 1024) {
        const int j = t & 7;
        const int lane = (t >> 3) & 63;
        const int nb = (t >> 9) & 7;
        const int kk = t >> 12;
        const int l16 = lane & 15, quad = lane >> 4;
        const int cn = nb * 16 + l16;
        const int h = cn & 63, part = cn >> 6;
        w1p[t] = f2bf(w1f[h * 1024 + part * 512 + kk * 32 + quad * 8 + j]);
    }
    if (blockIdx.x == 0 && threadIdx.x == 0) {
        int odd_nonzero = 0;
        for (int i = 0; i < 64; i++)
            if (nodes_i32[2 * i + 1] != 0) odd_nonzero++;
        *flag = (odd_nonzero == 0) ? 1 : 0;  // 1 => nodes is int64
    }
}

// Kernel A: PQ[n][c] (bf16): c<64 -> feat @ W1a^T ; c in [64,128) -> feat @ W1b^T
// M=32 rows per wave (2 m-tiles share each B fragment -> B-load:MFMA = 1:2).
// K grouped 2x2 with double-buffered A prefetch (8 x 16B loads in flight).
__global__ __launch_bounds__(256) void pq_gemm(const float* __restrict__ feat,
                                               const short* __restrict__ w1p,
                                               short* __restrict__ PQ) {
    const int wave = threadIdx.x >> 6;
    const int lane = threadIdx.x & 63;
    const int quad = lane >> 4;
    const int l16  = lane & 15;
    const int r0   = blockIdx.x * 128 + wave * 32;

    const float* aptr[2];
#pragma unroll
    for (int mt = 0; mt < 2; mt++) {
        int r = r0 + mt * 16 + l16;
        if (r >= N_NODES) r = N_NODES - 1;
        aptr[mt] = feat + (size_t)r * N_FEATS + quad * 8;
    }
    const short* bbase = w1p + lane * 8;

    f32x4 buf[2][2][4];
#pragma unroll
    for (int mt = 0; mt < 2; mt++)
#pragma unroll
        for (int kk2 = 0; kk2 < 2; kk2++) {
            buf[0][mt][kk2 * 2]     = *reinterpret_cast<const f32x4*>(aptr[mt] + kk2 * 32);
            buf[0][mt][kk2 * 2 + 1] = *reinterpret_cast<const f32x4*>(aptr[mt] + kk2 * 32 + 4);
        }

    f32x4 acc[2][8];
#pragma unroll
    for (int mt = 0; mt < 2; mt++)
#pragma unroll
        for (int i = 0; i < 8; i++) acc[mt][i] = (f32x4){0.f, 0.f, 0.f, 0.f};

#pragma unroll
    for (int g = 0; g < 8; g++) {
        const int cur = g & 1;
        if (g < 7) {  // prefetch next group's 2 k-steps for both m-tiles
#pragma unroll
            for (int mt = 0; mt < 2; mt++)
#pragma unroll
                for (int kk2 = 0; kk2 < 2; kk2++) {
                    buf[cur ^ 1][mt][kk2 * 2]     = *reinterpret_cast<const f32x4*>(aptr[mt] + (g + 1) * 64 + kk2 * 32);
                    buf[cur ^ 1][mt][kk2 * 2 + 1] = *reinterpret_cast<const f32x4*>(aptr[mt] + (g + 1) * 64 + kk2 * 32 + 4);
                }
        }
#pragma unroll
        for (int kk2 = 0; kk2 < 2; kk2++) {
            const int kk = g * 2 + kk2;
            bf16x8 afrag[2];
#pragma unroll
            for (int mt = 0; mt < 2; mt++)
#pragma unroll
                for (int j = 0; j < 4; j++) {
                    afrag[mt][j]     = f2bf(buf[cur][mt][kk2 * 2][j]);
                    afrag[mt][4 + j] = f2bf(buf[cur][mt][kk2 * 2 + 1][j]);
                }
            const short* bk = bbase + kk * 4096;
#pragma unroll
            for (int nb = 0; nb < 8; nb++) {
                bf16x8 bfrag = *reinterpret_cast<const bf16x8*>(bk + nb * 512);
                acc[0][nb] = __builtin_amdgcn_mfma_f32_16x16x32_bf16(afrag[0], bfrag, acc[0][nb], 0, 0, 0);
                acc[1][nb] = __builtin_amdgcn_mfma_f32_16x16x32_bf16(afrag[1], bfrag, acc[1][nb], 0, 0, 0);
            }
        }
    }

    // C/D layout (16x16x32): col(N) = lane&15 -> cn, row(M) = quad*4 + reg
#pragma unroll
    for (int mt = 0; mt < 2; mt++)
#pragma unroll
        for (int nb = 0; nb < 8; nb++) {
            const int cn = nb * 16 + l16;
#pragma unroll
            for (int r = 0; r < 4; r++) {
                const int row = r0 + mt * 16 + quad * 4 + r;
                if (row < N_NODES) PQ[(size_t)row * 128 + cn] = f2bf(acc[mt][nb][r]);
            }
        }
}

// Kernel B: h1[n][h] = relu(P[n][h] + 0.2*sum_s Q[neigh[n][s]][h]) IN-PLACE into
// PQ[n*128+h]. 8 threads/row, 16B/thread, 2 nodes per thread (n, n+50000) for
// 12 outstanding gathers. Writes cols 0..63 only; Q reads cols 64..127 only.
__global__ __launch_bounds__(256) void h1_combine(short* __restrict__ PQ,
                                                  const int* __restrict__ neigh_idx) {
    const int t = blockIdx.x * 256 + threadIdx.x;
    const int idx = t >> 3;
    const int sub = t & 7;
    if (idx >= 50000) return;
    const int n0 = idx, n1 = idx + 50000;

    u16x8 pv0 = *reinterpret_cast<const u16x8*>(PQ + (size_t)n0 * 128 + sub * 8);
    u16x8 pv1 = *reinterpret_cast<const u16x8*>(PQ + (size_t)n1 * 128 + sub * 8);

    int ni0[NUM_SAMPLES], ni1[NUM_SAMPLES];
#pragma unroll
    for (int i = 0; i < NUM_SAMPLES; i++) {
        ni0[i] = clampi(neigh_idx[n0 * NUM_SAMPLES + i]);
        ni1[i] = clampi(neigh_idx[n1 * NUM_SAMPLES + i]);
    }
    u16x8 qv0[NUM_SAMPLES], qv1[NUM_SAMPLES];
#pragma unroll
    for (int i = 0; i < NUM_SAMPLES; i++) {
        qv0[i] = *reinterpret_cast<const u16x8*>(PQ + (size_t)ni0[i] * 128 + 64 + sub * 8);
        qv1[i] = *reinterpret_cast<const u16x8*>(PQ + (size_t)ni1[i] * 128 + 64 + sub * 8);
    }

    u16x8 ov0, ov1;
#pragma unroll
    for (int j = 0; j < 8; j++) {
        float s0 = 0.f, s1 = 0.f;
#pragma unroll
        for (int i = 0; i < NUM_SAMPLES; i++) { s0 += bf2f(qv0[i][j]); s1 += bf2f(qv1[i][j]); }
        float v0 = bf2f(pv0[j]) + 0.2f * s0;
        float v1 = bf2f(pv1[j]) + 0.2f * s1;
        ov0[j] = (unsigned short)f2bf(v0 > 0.f ? v0 : 0.f);
        ov1[j] = (unsigned short)f2bf(v1 > 0.f ? v1 : 0.f);
    }
    *reinterpret_cast<u16x8*>(PQ + (size_t)n0 * 128 + sub * 8) = ov0;
    *reinterpret_cast<u16x8*>(PQ + (size_t)n1 * 128 + sub * 8) = ov1;
}

// Kernel C: 32 batch items per block (8 per wave). g = concat(h1[node],
// 0.2*sum_s h1[neigh[node][s]]); h2 = relu(g @ w2^T); out = h2 @ wcls^T (fp32).
__global__ __launch_bounds__(256) void layer2_cls(const short* __restrict__ PQ,
                                                  const int* __restrict__ nodes_i32,
                                                  const int* __restrict__ neigh_idx,
                                                  const float* __restrict__ w2,
                                                  const float* __restrict__ wcls,
                                                  const int* __restrict__ flag,
                                                  float* __restrict__ out) {
    __shared__ float gbuf[32][128];
    __shared__ float h2buf[32][64];
    const int wave = threadIdx.x >> 6;
    const int lane = threadIdx.x & 63;
    const int is64 = *flag;
    const int b0 = blockIdx.x * 32;

#pragma unroll
    for (int it = 0; it < 8; it++) {
        const int item = wave * 8 + it;
        const int b = b0 + item;
        const int node = clampi(nodes_i32[is64 ? 2 * b : b]);
        float selfv = bf2f((unsigned short)PQ[(size_t)node * 128 + lane]);
        float ns = 0.f;
#pragma unroll
        for (int s = 0; s < NUM_SAMPLES; s++) {
            const int ni = clampi(neigh_idx[node * NUM_SAMPLES + s]);
            ns += bf2f((unsigned short)PQ[(size_t)ni * 128 + lane]);
        }
        gbuf[item][lane] = selfv;
        gbuf[item][64 + lane] = 0.2f * ns;
    }
    __syncthreads();

    float acc[8] = {0.f, 0.f, 0.f, 0.f, 0.f, 0.f, 0.f, 0.f};
    const f32x4* w2r = reinterpret_cast<const f32x4*>(w2 + lane * 128);
#pragma unroll 8
    for (int k = 0; k < 32; k++) {
        f32x4 w = w2r[k];
#pragma unroll
        for (int it = 0; it < 8; it++) {
            f32x4 g = *reinterpret_cast<const f32x4*>(&gbuf[wave * 8 + it][k * 4]);
            acc[it] += g[0] * w[0] + g[1] * w[1] + g[2] * w[2] + g[3] * w[3];
        }
    }
#pragma unroll
    for (int it = 0; it < 8; it++) {
        float h2 = acc[it] > 0.f ? acc[it] : 0.f;
        h2buf[wave * 8 + it][lane] = h2;
    }
    __syncthreads();

    if (lane < NUM_CLASSES) {
        const f32x4* wcr = reinterpret_cast<const f32x4*>(wcls + lane * 64);
#pragma unroll
        for (int it = 0; it < 8; it++) {
            const int item = wave * 8 + it;
            const f32x4* hr = reinterpret_cast<const f32x4*>(&h2buf[item][0]);
            float o = 0.f;
#pragma unroll
            for (int k = 0; k < 16; k++) {
                f32x4 h = hr[k], w = wcr[k];
                o += h[0] * w[0] + h[1] * w[1] + h[2] * w[2] + h[3] * w[3];
            }
            out[(size_t)(b0 + item) * NUM_CLASSES + lane] = o;
        }
    }
}

extern "C" void kernel_launch(void* const* d_in, const int* in_sizes, int n_in,
                              void* d_out, int out_size, void* d_ws, size_t ws_size,
                              hipStream_t stream) {
    const float* feat = nullptr;      // 100000*512  = 51,200,000
    const float* w1 = nullptr;        // 64*1024     = 65,536
    const float* w2 = nullptr;        // 64*128      = 8,192
    const float* wcls = nullptr;      // 16*64       = 1,024
    const int* nodes = nullptr;       // 16,384
    const int* neigh_idx = nullptr;   // 100000*5    = 500,000
    for (int i = 0; i < n_in; i++) {
        switch (in_sizes[i]) {
            case 51200000: feat = (const float*)d_in[i]; break;
            case 65536:    w1 = (const float*)d_in[i]; break;
            case 8192:     w2 = (const float*)d_in[i]; break;
            case 1024:     wcls = (const float*)d_in[i]; break;
            case 16384:    nodes = (const int*)d_in[i]; break;
            case 500000:   neigh_idx = (const int*)d_in[i]; break;
            default: break;
        }
    }
    float* out = (float*)d_out;  // [16384,16] fp32

    // ws layout: [0..4) nodes-dtype flag; [256 ..) packed w1 bf16 (131072 B);
    // then PQ bf16 [100000][128] (25.6 MB).
    int* flag = (int*)d_ws;
    short* w1p = (short*)((char*)d_ws + 256);
    short* PQ  = (short*)((char*)d_ws + 256 + 64 * 1024 * sizeof(short));

    prep<<<256, 256, 0, stream>>>(w1, w1p, nodes, flag);
    pq_gemm<<<(N_NODES + 127) / 128, 256, 0, stream>>>(feat, w1p, PQ);
    h1_combine<<<(50000 * 8 + 255) / 256, 256, 0, stream>>>(PQ, neigh_idx);
    layer2_cls<<<BATCH / 32, 256, 0, stream>>>(PQ, nodes, neigh_idx, w2, wcls, flag, out);
}